// Round 13
// baseline (157.324 us; speedup 1.0000x reference)
//
#include <hip/hip_runtime.h>
#include <hip/hip_fp16.h>

static constexpr int F = 64;      // IN_FEATS == HIDDEN
static constexpr int C = 16;      // NUM_CLASSES
static constexpr int EPB = 2048;  // edges per block (hist/partition)
static constexpr int BSH = 9;     // bucket shift: 512 nodes/bucket
static constexpr int SRCB = 17;   // src id bits (nNodes <= 131072)
static constexpr int NPG = 4;     // nodes per lane-group (gathers)

// -------- prep: fp32->fp16 convert + per-block histogram + SLICE RESERVATION
// (byte-identical to round 12 — proven)
__global__ void prep(const float* __restrict__ x, __half* __restrict__ xh, int n4,
                     const int* __restrict__ dst, int* __restrict__ bucketCount,
                     int* __restrict__ blockHist, int nEdges) {
    int stride = gridDim.x * blockDim.x;
    for (int i = blockIdx.x * blockDim.x + threadIdx.x; i < n4; i += stride) {
        float4 v = ((const float4*)x)[i];
        __half2 p0 = __floats2half2_rn(v.x, v.y);
        __half2 p1 = __floats2half2_rn(v.z, v.w);
        uint2 o;
        o.x = *reinterpret_cast<unsigned*>(&p0);
        o.y = *reinterpret_cast<unsigned*>(&p1);
        ((uint2*)xh)[i] = o;
    }
    __shared__ int h[256];
    int t = threadIdx.x;
    h[t] = 0;
    __syncthreads();
    int e0 = blockIdx.x * EPB;
    for (int i = 0; i < EPB / 256; ++i) {
        int e = e0 + i * 256 + t;
        if (e < nEdges) atomicAdd(&h[dst[e] >> BSH], 1);
    }
    __syncthreads();
    blockHist[blockIdx.x * 256 + t] = h[t] ? atomicAdd(&bucketCount[t], h[t]) : 0;
}

// ------------- partition: place edges into pre-reserved bucket slices
// (bucket scan computed in-block from bucketCount — no separate scan kernel)
__global__ void partition(const int* __restrict__ src, const int* __restrict__ dst,
                          const int* __restrict__ blockHist,
                          const int* __restrict__ bucketCount,
                          unsigned* __restrict__ pairs, int nEdges) {
    __shared__ int s[256];
    __shared__ int base[256];
    __shared__ int rank[256];
    int t = threadIdx.x;
    s[t] = bucketCount[t];
    rank[t] = 0;
    __syncthreads();
    for (int o = 1; o < 256; o <<= 1) {        // inclusive scan
        int v = (t >= o) ? s[t - o] : 0;
        __syncthreads();
        s[t] += v;
        __syncthreads();
    }
    int bstart = (t > 0) ? s[t - 1] : 0;       // exclusive
    base[t] = bstart + blockHist[blockIdx.x * 256 + t];
    __syncthreads();
    int e0 = blockIdx.x * EPB;
    for (int i = 0; i < EPB / 256; ++i) {
        int e = e0 + i * 256 + t;
        if (e < nEdges) {
            int d = dst[e];
            int b = d >> BSH;
            int r = atomicAdd(&rank[b], 1);
            pairs[base[b] + r] =
                ((unsigned)(d & ((1 << BSH) - 1)) << SRCB) | (unsigned)src[e];
        }
    }
}

// ------- per-bucket: degrees -> local scan -> rowstart + csr (single writer)
// (bucket scan computed in-block from bucketCount)
__global__ void bucket_csr(const unsigned* __restrict__ pairs,
                           const int* __restrict__ bucketCount,
                           int* __restrict__ rowstart, int* __restrict__ csr,
                           int nNodes, int nEdges) {
    __shared__ int bscan[256];
    __shared__ int cnt[512];
    __shared__ int s[512];
    __shared__ int cur[512];
    int t = threadIdx.x;
    int b = blockIdx.x;
    if (t < 256) bscan[t] = bucketCount[t];
    __syncthreads();
    for (int o = 1; o < 256; o <<= 1) {        // inclusive scan (t<256 active)
        int v = (t < 256 && t >= o) ? bscan[t - o] : 0;
        __syncthreads();
        if (t < 256) bscan[t] += v;
        __syncthreads();
    }
    int pBeg = (b > 0) ? bscan[b - 1] : 0;
    int pEnd = bscan[b];
    int nodeBase = b << BSH;
    cnt[t] = 0;
    __syncthreads();
    for (int i = pBeg + t; i < pEnd; i += 512)
        atomicAdd(&cnt[pairs[i] >> SRCB], 1);
    __syncthreads();
    s[t] = cnt[t];
    __syncthreads();
    for (int o = 1; o < 512; o <<= 1) {
        int v = (t >= o) ? s[t - o] : 0;
        __syncthreads();
        s[t] += v;
        __syncthreads();
    }
    int rs = pBeg + ((t > 0) ? s[t - 1] : 0);
    int node = nodeBase + t;
    if (node < nNodes) rowstart[node] = rs;
    cur[t] = rs;
    __syncthreads();
    for (int i = pBeg + t; i < pEnd; i += 512) {
        unsigned p = pairs[i];
        int pos = atomicAdd(&cur[p >> SRCB], 1);
        csr[pos] = (int)(p & ((1u << SRCB) - 1));
    }
    if (b == 0 && t == 0) rowstart[nNodes] = nEdges;
}

// --------------- unpack-accumulate one 16B (8-half) chunk into 8 fp32 accs
__device__ __forceinline__ void acc8(float* a, uint4 u) {
    __half2 h0 = *reinterpret_cast<__half2*>(&u.x);
    __half2 h1 = *reinterpret_cast<__half2*>(&u.y);
    __half2 h2 = *reinterpret_cast<__half2*>(&u.z);
    __half2 h3 = *reinterpret_cast<__half2*>(&u.w);
    a[0] += __low2float(h0); a[1] += __high2float(h0);
    a[2] += __low2float(h1); a[3] += __high2float(h1);
    a[4] += __low2float(h2); a[5] += __high2float(h2);
    a[6] += __low2float(h3); a[7] += __high2float(h3);
}

// ---- gather_h8: 8-lane group owns NPG consecutive nodes; lane q = 16B chunk q.
// uint4 loads (16B/lane), 8 node-streams/wave, 4-deep chains, no LDS/barriers.
__global__ void gather_h8(const __half* __restrict__ xh,
                          const int* __restrict__ rowstart,
                          const int* __restrict__ csr,
                          float* __restrict__ agg, int nNodes) {
    int gid = (blockIdx.x * blockDim.x + threadIdx.x) >> 3;
    int q = threadIdx.x & 7;
    int nodeBase = gid * NPG;
    if (nodeBase >= nNodes) return;
    const uint4* x4 = (const uint4*)xh;        // row = 8 x uint4 (128B)
    int rs[NPG + 1];
#pragma unroll
    for (int i = 0; i <= NPG; ++i) rs[i] = rowstart[min(nodeBase + i, nNodes)];
#pragma unroll
    for (int i = 0; i < NPG; ++i) {
        int node = nodeBase + i;
        if (node >= nNodes) break;
        int beg = rs[i], end = rs[i + 1];
        float a0[8] = {0,0,0,0,0,0,0,0};
        float a1[8] = {0,0,0,0,0,0,0,0};
        float a2[8] = {0,0,0,0,0,0,0,0};
        float a3[8] = {0,0,0,0,0,0,0,0};
        int k = beg;
        for (; k + 4 <= end; k += 4) {         // 4 independent row chains
            int s0 = csr[k], s1 = csr[k + 1], s2 = csr[k + 2], s3 = csr[k + 3];
            uint4 u0 = x4[(size_t)s0 * 8 + q];
            uint4 u1 = x4[(size_t)s1 * 8 + q];
            uint4 u2 = x4[(size_t)s2 * 8 + q];
            uint4 u3 = x4[(size_t)s3 * 8 + q];
            acc8(a0, u0); acc8(a1, u1); acc8(a2, u2); acc8(a3, u3);
        }
        for (; k < end; ++k)                   // tail
            acc8(a0, x4[(size_t)csr[k] * 8 + q]);
        float inv = 1.0f / fmaxf((float)(end - beg), 1.0f);
        float4 o0, o1;
        o0.x = ((a0[0] + a1[0]) + (a2[0] + a3[0])) * inv;
        o0.y = ((a0[1] + a1[1]) + (a2[1] + a3[1])) * inv;
        o0.z = ((a0[2] + a1[2]) + (a2[2] + a3[2])) * inv;
        o0.w = ((a0[3] + a1[3]) + (a2[3] + a3[3])) * inv;
        o1.x = ((a0[4] + a1[4]) + (a2[4] + a3[4])) * inv;
        o1.y = ((a0[5] + a1[5]) + (a2[5] + a3[5])) * inv;
        o1.z = ((a0[6] + a1[6]) + (a2[6] + a3[6])) * inv;
        o1.w = ((a0[7] + a1[7]) + (a2[7] + a3[7])) * inv;
        ((float4*)agg)[(size_t)node * 16 + q * 2]     = o0;   // 256B/row coalesced
        ((float4*)agg)[(size_t)node * 16 + q * 2 + 1] = o1;
    }
}

// ---- dense12_reg: t2 = relu(agg@W1+b1)@W2, weights in registers (round 10/12)
__global__ void dense12_reg(const float* __restrict__ agg,
                            const float* __restrict__ W1,
                            const float* __restrict__ b1,
                            const float* __restrict__ W2,
                            __half* __restrict__ t2, int nNodes) {
    __shared__ float xs[4][F];
    __shared__ float hs[4][F];
    __shared__ float red[4][4][17];
    int wave = threadIdx.x >> 6, lane = threadIdx.x & 63;
    int kk = lane >> 4, c = lane & 15;

    float w1[F];
#pragma unroll
    for (int k = 0; k < F; ++k) w1[k] = W1[k * F + lane];
    float b1l = b1[lane];
    float w2[16];
#pragma unroll
    for (int j = 0; j < 16; ++j) w2[j] = W2[(kk * 16 + j) * C + c];

    int step = gridDim.x * 4;
    int start = blockIdx.x * 4 + wave;
    int iters = (nNodes + step - 1) / step;
    for (int i = 0; i < iters; ++i) {
        int node = start + i * step;
        bool live = node < nNodes;
        xs[wave][lane] = live ? agg[(size_t)node * F + lane] : 0.0f;
        __syncthreads();
        float hacc = b1l;
#pragma unroll
        for (int k = 0; k < F; ++k) hacc = fmaf(xs[wave][k], w1[k], hacc);
        hs[wave][lane] = fmaxf(hacc, 0.0f);
        __syncthreads();
        float p = 0.0f;
#pragma unroll
        for (int j = 0; j < 16; ++j) p = fmaf(hs[wave][kk * 16 + j], w2[j], p);
        red[wave][kk][c] = p;
        __syncthreads();
        if (lane < C && live) {
            float o = red[wave][0][lane] + red[wave][1][lane]
                    + red[wave][2][lane] + red[wave][3][lane];
            t2[(size_t)node * C + lane] = __float2half_rn(o);
        }
        __syncthreads();
    }
}

// ---- gather16_4: 4-lane group per node-stream; lane q = 8B (4-half) chunk q.
// 16 node-streams/wave; float4 output store with bias folded in.
__global__ void gather16_4(const __half* __restrict__ t2,
                           const int* __restrict__ rowstart,
                           const int* __restrict__ csr,
                           const float* __restrict__ b2,
                           float* __restrict__ out, int nNodes) {
    int gid = (blockIdx.x * blockDim.x + threadIdx.x) >> 2;
    int q = threadIdx.x & 3;
    int nodeBase = gid * NPG;
    if (nodeBase >= nNodes) return;
    const uint2* t2v = (const uint2*)t2;       // row = 4 x uint2 (32B)
    float4 b2v = ((const float4*)b2)[q];
    int rs[NPG + 1];
#pragma unroll
    for (int i = 0; i <= NPG; ++i) rs[i] = rowstart[min(nodeBase + i, nNodes)];
#pragma unroll
    for (int i = 0; i < NPG; ++i) {
        int node = nodeBase + i;
        if (node >= nNodes) break;
        int beg = rs[i], end = rs[i + 1];
        float a0[4] = {0,0,0,0}, a1[4] = {0,0,0,0};
        float a2[4] = {0,0,0,0}, a3[4] = {0,0,0,0};
        int k = beg;
        for (; k + 4 <= end; k += 4) {
            int s0 = csr[k], s1 = csr[k + 1], s2 = csr[k + 2], s3 = csr[k + 3];
            uint2 u0 = t2v[(size_t)s0 * 4 + q];
            uint2 u1 = t2v[(size_t)s1 * 4 + q];
            uint2 u2 = t2v[(size_t)s2 * 4 + q];
            uint2 u3 = t2v[(size_t)s3 * 4 + q];
            __half2 p, r;
            p = *reinterpret_cast<__half2*>(&u0.x); r = *reinterpret_cast<__half2*>(&u0.y);
            a0[0] += __low2float(p); a0[1] += __high2float(p);
            a0[2] += __low2float(r); a0[3] += __high2float(r);
            p = *reinterpret_cast<__half2*>(&u1.x); r = *reinterpret_cast<__half2*>(&u1.y);
            a1[0] += __low2float(p); a1[1] += __high2float(p);
            a1[2] += __low2float(r); a1[3] += __high2float(r);
            p = *reinterpret_cast<__half2*>(&u2.x); r = *reinterpret_cast<__half2*>(&u2.y);
            a2[0] += __low2float(p); a2[1] += __high2float(p);
            a2[2] += __low2float(r); a2[3] += __high2float(r);
            p = *reinterpret_cast<__half2*>(&u3.x); r = *reinterpret_cast<__half2*>(&u3.y);
            a3[0] += __low2float(p); a3[1] += __high2float(p);
            a3[2] += __low2float(r); a3[3] += __high2float(r);
        }
        for (; k < end; ++k) {
            uint2 u0 = t2v[(size_t)csr[k] * 4 + q];
            __half2 p = *reinterpret_cast<__half2*>(&u0.x);
            __half2 r = *reinterpret_cast<__half2*>(&u0.y);
            a0[0] += __low2float(p); a0[1] += __high2float(p);
            a0[2] += __low2float(r); a0[3] += __high2float(r);
        }
        float dinv = 1.0f / fmaxf((float)(end - beg), 1.0f);
        float4 o;
        o.x = ((a0[0] + a1[0]) + (a2[0] + a3[0])) * dinv + b2v.x;
        o.y = ((a0[1] + a1[1]) + (a2[1] + a3[1])) * dinv + b2v.y;
        o.z = ((a0[2] + a1[2]) + (a2[2] + a3[2])) * dinv + b2v.z;
        o.w = ((a0[3] + a1[3]) + (a2[3] + a3[3])) * dinv + b2v.w;
        ((float4*)out)[(size_t)node * 4 + q] = o;
    }
}

// ---------------------------------------------------------------- launch
extern "C" void kernel_launch(void* const* d_in, const int* in_sizes, int n_in,
                              void* d_out, int out_size, void* d_ws, size_t ws_size,
                              hipStream_t stream) {
    const float* features = (const float*)d_in[0];
    const int*   src      = (const int*)d_in[1];
    const int*   dst      = (const int*)d_in[2];
    const float* W1       = (const float*)d_in[3];
    const float* b1       = (const float*)d_in[4];
    const float* W2       = (const float*)d_in[5];
    const float* b2       = (const float*)d_in[6];
    float*       out      = (float*)d_out;

    const int nNodes = in_sizes[0] / F;           // 100000
    const int nEdges = in_sizes[1];               // 1600000
    const int NBUCK = (nNodes + 511) >> BSH;      // 196 (<= 256)
    const int NBLK  = (nEdges + EPB - 1) / EPB;   // 782

    // ---- workspace carve-up (peak ~49.6 MiB; round-1 proved >=51.6 MiB works)
    char* ws = (char*)d_ws;
    auto align = [](size_t x) { return (x + 255) / 256 * 256; };
    int* bucketCount  = (int*)ws;    ws += align(256 * 4);
    int* blockHist    = (int*)ws;    ws += align((size_t)NBLK * 256 * 4);
    int* rowstart     = (int*)ws;    ws += align((size_t)(nNodes + 1) * 4);
    int* csr          = (int*)ws;    ws += align((size_t)nEdges * 4);
    __half* xh        = (__half*)ws; ws += align((size_t)nNodes * F * 2);
    float* agg        = (float*)ws;  ws += align((size_t)nNodes * F * 4);
    __half* t2h       = (__half*)ws; ws += align((size_t)nNodes * C * 2);
    unsigned* pairs   = (unsigned*)agg;  // 6.4 MB inside agg; dead before gather

    hipMemsetAsync(bucketCount, 0, 256 * sizeof(int), stream);

    // ---- prep (convert + hist + slice reservation) then CSR build (2 kernels)
    prep<<<NBLK, 256, 0, stream>>>(features, xh, nNodes * F / 4,
                                   dst, bucketCount, blockHist, nEdges);
    partition<<<NBLK, 256, 0, stream>>>(src, dst, blockHist, bucketCount, pairs, nEdges);
    bucket_csr<<<NBUCK, 512, 0, stream>>>(pairs, bucketCount, rowstart, csr,
                                          nNodes, nEdges);

    // ---- layer 1 gather (8-lane groups, 16B loads) + register-resident dense
    {
        int nGroups = (nNodes + NPG - 1) / NPG;            // 25000
        int blocks = (nGroups * 8 + 255) / 256;            // 782
        gather_h8<<<blocks, 256, 0, stream>>>(xh, rowstart, csr, agg, nNodes);
    }
    dense12_reg<<<2048, 256, 0, stream>>>(agg, W1, b1, W2, t2h, nNodes);

    // ---- layer 2 aggregation (4-lane groups, 8B loads)
    {
        int nGroups = (nNodes + NPG - 1) / NPG;
        int blocks = (nGroups * 4 + 255) / 256;            // 391
        gather16_4<<<blocks, 256, 0, stream>>>(t2h, rowstart, csr, b2, out, nNodes);
    }
}